// Round 5
// baseline (207.255 us; speedup 1.0000x reference)
//
#include <hip/hip_runtime.h>

#define H 64
#define NPIX 65536
#define LBATCH 8
#define LC 24
#define S_CHUNKS 64
#define PB 1024            // pixels per block
#define EPSF 1e-6f
#define LN2_50 34.6573590f // 50 * ln(2): U50 = 50*(ln a - ln b) = LN2_50*(log2 a - log2 b)

typedef _Float16 h8 __attribute__((ext_vector_type(8)));   // MFMA operand
typedef _Float16 h4 __attribute__((ext_vector_type(4)));
typedef _Float16 h2 __attribute__((ext_vector_type(2)));
typedef short    s2 __attribute__((ext_vector_type(2)));
typedef float f32x16 __attribute__((ext_vector_type(16)));
union H8p { h8 v8; h2 h[4]; };

#if __has_builtin(__builtin_elementwise_fma)
#define FMA2(a, b, c) __builtin_elementwise_fma((a), (b), (c))
#else
#define FMA2(a, b, c) ((a) * (b) + (c))
#endif

// Full-rate packed-fp16 eval of 1/(1+d^2), d = u - o, x clamped to 16384
// (values past d~128 are <=6e-5; normalization shift ~1e-5, analyzed safe).
// Reciprocal = int-magic seed + 2 packed Newton steps -> ZERO trans-pipe ops.
static __device__ __forceinline__ h2 kev2(h2 u2, h2 o2, h2 one2, h2 two2,
                                          h2 clamp2, s2 magic2) {
    const h2 d  = u2 - o2;                                        // v_pk_add (neg)
    const h2 xx = __builtin_elementwise_min(FMA2(d, d, one2), clamp2);
    h2 y = __builtin_bit_cast(h2, (s2)(magic2 - __builtin_bit_cast(s2, xx)));
    y = y * FMA2(-xx, y, two2);                                   // Newton 1
    y = y * FMA2(-xx, y, two2);                                   // Newton 2
    return y;
}

__global__ __launch_bounds__(256) void hist_zero(float* __restrict__ out) {
    out[blockIdx.x * 256 + threadIdx.x] = 0.0f;
}

// One block per (lc, 1024-pixel chunk). Phase 1: stage fp16 U50/V50/w (6 KB).
// Phase 2: 16 K-steps of (3 broadcast ds_read_b128 -> 136 pk-ops -> 4 MFMA).
// LDS 22 KB, ~114 unified regs -> 4 blocks/CU resident.
__global__ __launch_bounds__(256, 4) void hist_main(const float* __restrict__ x,
                                                    float* __restrict__ out) {
    __shared__ _Float16 sUh[PB];
    __shared__ _Float16 sVh[PB];
    __shared__ _Float16 sWh[PB];
    __shared__ float sHist[H * H];

    const int tid  = threadIdx.x;
    const int wv   = tid >> 6;
    const int lane = tid & 63;
    const int hf   = lane >> 5;
    const int ln   = lane & 31;
    const int lc   = blockIdx.y;
    const int l    = lc / 3;
    const int c    = lc - 3 * l;

    #pragma unroll
    for (int r = 0; r < 4; r++)
        *(float4*)&sHist[(r * 256 + tid) * 4] = make_float4(0.f, 0.f, 0.f, 0.f);

    const float* __restrict__ x0p = x + (l * 3 + 0) * NPIX;
    const float* __restrict__ x1p = x + (l * 3 + 1) * NPIX;
    const float* __restrict__ x2p = x + (l * 3 + 2) * NPIX;
    const int base = blockIdx.x * PB;

    // ---- Phase 1: prep 4 px/thread, store fp16 ----
    {
        const int ploc = tid * 4;
        const float4 r0 = *(const float4*)&x0p[base + ploc];
        const float4 r1 = *(const float4*)&x1p[base + ploc];
        const float4 r2 = *(const float4*)&x2p[base + ploc];
        float4 U4, V4, W4;
        #define PREP(E) { \
            const float v0 = fminf(fmaxf(r0.E, 0.0f), 1.0f); \
            const float v1 = fminf(fmaxf(r1.E, 0.0f), 1.0f); \
            const float v2 = fminf(fmaxf(r2.E, 0.0f), 1.0f); \
            W4.E = __builtin_amdgcn_sqrtf(fmaf(v0, v0, fmaf(v1, v1, fmaf(v2, v2, EPSF)))); \
            const float lg0 = __builtin_amdgcn_logf(v0 + EPSF); \
            const float lg1 = __builtin_amdgcn_logf(v1 + EPSF); \
            const float lg2 = __builtin_amdgcn_logf(v2 + EPSF); \
            float U, V; \
            if (c == 0)      { U = lg0 - lg1; V = lg0 - lg2; } \
            else if (c == 1) { U = lg1 - lg0; V = lg1 - lg2; } \
            else             { U = lg2 - lg0; V = lg2 - lg1; } \
            U4.E = LN2_50 * U; V4.E = LN2_50 * V; }
        PREP(x) PREP(y) PREP(z) PREP(w)
        #undef PREP
        *(h4*)&sUh[ploc] = h4{(_Float16)U4.x, (_Float16)U4.y, (_Float16)U4.z, (_Float16)U4.w};
        *(h4*)&sVh[ploc] = h4{(_Float16)V4.x, (_Float16)V4.y, (_Float16)V4.z, (_Float16)V4.w};
        *(h4*)&sWh[ploc] = h4{(_Float16)W4.x, (_Float16)W4.y, (_Float16)W4.z, (_Float16)W4.w};
    }
    __syncthreads();

    // ---- Phase 2: packed-fp16 eval + MFMA ----
    const float step50 = 50.0f * (6.0f / 63.0f);
    const float ou0 = -150.0f + step50 * (float)ln;
    const float ou1 = ou0 + step50 * 32.0f;
    const _Float16 oh0 = (_Float16)ou0;
    const _Float16 oh1 = (_Float16)ou1;
    const h2 o0_2 = {oh0, oh0};
    const h2 o1_2 = {oh1, oh1};
    const h2 one2   = {(_Float16)1.0f, (_Float16)1.0f};
    const h2 two2   = {(_Float16)2.0f, (_Float16)2.0f};
    const h2 clamp2 = {(_Float16)16384.0f, (_Float16)16384.0f};
    const s2 magic2 = {(short)0x779A, (short)0x779A};

    f32x16 acc00, acc01, acc10, acc11;
    #pragma unroll
    for (int i = 0; i < 16; i++) { acc00[i] = 0.f; acc01[i] = 0.f; acc10[i] = 0.f; acc11[i] = 0.f; }

    const int wbase = wv * 256;
    #pragma unroll 2
    for (int ks = 0; ks < 16; ks++) {
        const int kb = wbase + ks * 16 + hf * 8;     // half-wave's 8 k-pixels
        H8p U, V, W, A0, A1, B0, B1;
        U.v8 = *(const h8*)&sUh[kb];
        V.v8 = *(const h8*)&sVh[kb];
        W.v8 = *(const h8*)&sWh[kb];
        #pragma unroll
        for (int q = 0; q < 4; q++) {
            A0.h[q] = W.h[q] * kev2(U.h[q], o0_2, one2, two2, clamp2, magic2);
            A1.h[q] = W.h[q] * kev2(U.h[q], o1_2, one2, two2, clamp2, magic2);
            B0.h[q] = kev2(V.h[q], o0_2, one2, two2, clamp2, magic2);
            B1.h[q] = kev2(V.h[q], o1_2, one2, two2, clamp2, magic2);
        }
        acc00 = __builtin_amdgcn_mfma_f32_32x32x16_f16(A0.v8, B0.v8, acc00, 0, 0, 0);
        acc01 = __builtin_amdgcn_mfma_f32_32x32x16_f16(A0.v8, B1.v8, acc01, 0, 0, 0);
        acc10 = __builtin_amdgcn_mfma_f32_32x32x16_f16(A1.v8, B0.v8, acc10, 0, 0, 0);
        acc11 = __builtin_amdgcn_mfma_f32_32x32x16_f16(A1.v8, B1.v8, acc11, 0, 0, 0);
    }

    // merge 4 wave accumulators (C/D layout: col=ln, row=(r&3)+8*(r>>2)+4*hf)
    #pragma unroll
    for (int r = 0; r < 16; r++) {
        const int row = (r & 3) + 8 * (r >> 2) + 4 * hf;
        atomicAdd(&sHist[row * 64 + ln],             acc00[r]);
        atomicAdd(&sHist[row * 64 + 32 + ln],        acc01[r]);
        atomicAdd(&sHist[(row + 32) * 64 + ln],      acc10[r]);
        atomicAdd(&sHist[(row + 32) * 64 + 32 + ln], acc11[r]);
    }
    __syncthreads();

    float* __restrict__ g = out + lc * (H * H);
    #pragma unroll
    for (int r = 0; r < 16; r++) {
        const int i = r * 256 + tid;
        unsafeAtomicAdd(&g[i], sHist[i]);
    }
}

// fused total + normalize: one block per sample l
__global__ __launch_bounds__(256) void hist_finish(float* __restrict__ out) {
    const int l = blockIdx.x;
    float* __restrict__ p = out + l * 3 * H * H;
    float s = 0.0f;
    #pragma unroll
    for (int it = 0; it < 12; it++) {
        const float4 v = *(const float4*)&p[(it * 256 + threadIdx.x) * 4];
        s += (v.x + v.y) + (v.z + v.w);
    }
    #pragma unroll
    for (int off = 32; off > 0; off >>= 1) s += __shfl_down(s, off, 64);
    __shared__ float ps[4];
    if ((threadIdx.x & 63) == 0) ps[threadIdx.x >> 6] = s;
    __syncthreads();
    const float T = (ps[0] + ps[1]) + (ps[2] + ps[3]);
    const float inv = 1.0f / (T + EPSF);
    #pragma unroll
    for (int it = 0; it < 12; it++) {
        float4 v = *(const float4*)&p[(it * 256 + threadIdx.x) * 4];
        v.x *= inv; v.y *= inv; v.z *= inv; v.w *= inv;
        *(float4*)&p[(it * 256 + threadIdx.x) * 4] = v;
    }
}

extern "C" void kernel_launch(void* const* d_in, const int* in_sizes, int n_in,
                              void* d_out, int out_size, void* d_ws, size_t ws_size,
                              hipStream_t stream) {
    const float* x = (const float*)d_in[0];
    float* out = (float*)d_out;

    hipLaunchKernelGGL(hist_zero,   dim3(LC * H * H / 256), dim3(256), 0, stream, out);
    hipLaunchKernelGGL(hist_main,   dim3(S_CHUNKS, LC),     dim3(256), 0, stream, x, out);
    hipLaunchKernelGGL(hist_finish, dim3(LBATCH),           dim3(256), 0, stream, out);
}

// Round 6
// 154.164 us; speedup vs baseline: 1.3444x; 1.3444x over previous
//
#include <hip/hip_runtime.h>

#define H 64
#define NPIX 65536
#define LBATCH 8
#define LC 24
#define S_CHUNKS 32
#define PB 2048            // pixels per block
#define EPSF 1e-6f
#define LN2_50 34.6573590f // 50 * ln(2): U50 = 50*(ln a - ln b) = LN2_50*(log2 a - log2 b)

// ws bytes needed for the non-atomic (partials) path
#define NEED_WS ((size_t)S_CHUNKS * LC * H * H * 4)

typedef _Float16 h8 __attribute__((ext_vector_type(8)));   // MFMA operand
typedef _Float16 h4 __attribute__((ext_vector_type(4)));
typedef _Float16 h2 __attribute__((ext_vector_type(2)));
typedef short    s2 __attribute__((ext_vector_type(2)));
typedef float f32x16 __attribute__((ext_vector_type(16)));
union H8p { h8 v8; h2 h[4]; };

#if __has_builtin(__builtin_elementwise_fma)
#define FMA2(a, b, c) __builtin_elementwise_fma((a), (b), (c))
#else
#define FMA2(a, b, c) ((a) * (b) + (c))
#endif

// Full-rate packed-fp16 eval of 1/(1+d^2): int-magic seed + 2 packed Newton
// steps. Zero trans-pipe ops. x clamped to 16384 (tail values <=6e-5).
static __device__ __forceinline__ h2 kev2(h2 u2, h2 o2, h2 one2, h2 two2,
                                          h2 clamp2, s2 magic2) {
    const h2 d  = u2 - o2;
    const h2 xx = __builtin_elementwise_min(FMA2(d, d, one2), clamp2);
    h2 y = __builtin_bit_cast(h2, (s2)(magic2 - __builtin_bit_cast(s2, xx)));
    y = y * FMA2(-xx, y, two2);
    y = y * FMA2(-xx, y, two2);
    return y;
}

__global__ __launch_bounds__(256) void hist_zero(float* __restrict__ out) {
    out[blockIdx.x * 256 + threadIdx.x] = 0.0f;
}

// One block per (lc, 2048-px chunk). Phase 1: stage fp16 U50/V50/w (12 KB).
// Phase 2: 32 K-steps/wave of (3 broadcast ds_read_b128 -> 136 pk-ops ->
// 4 mfma_f32_32x32x16_f16). Epilogue: LDS merge, then EITHER plain coalesced
// partial stores to ws (mode 0 -- no global atomics; they RMW at the
// memory-side coherence point at ~220 GB/s and dominated R2-R5) OR atomic
// accumulate into out (mode 1 fallback if ws too small).
__global__ __launch_bounds__(256, 4) void hist_main(const float* __restrict__ x,
                                                    float* __restrict__ dst,
                                                    int atomic_mode) {
    __shared__ _Float16 sUh[PB];
    __shared__ _Float16 sVh[PB];
    __shared__ _Float16 sWh[PB];
    __shared__ float sHist[H * H];

    const int tid  = threadIdx.x;
    const int wv   = tid >> 6;
    const int lane = tid & 63;
    const int hf   = lane >> 5;
    const int ln   = lane & 31;
    const int lc   = blockIdx.y;
    const int l    = lc / 3;
    const int c    = lc - 3 * l;

    #pragma unroll
    for (int r = 0; r < 4; r++)
        *(float4*)&sHist[(r * 256 + tid) * 4] = make_float4(0.f, 0.f, 0.f, 0.f);

    const float* __restrict__ x0p = x + (l * 3 + 0) * NPIX;
    const float* __restrict__ x1p = x + (l * 3 + 1) * NPIX;
    const float* __restrict__ x2p = x + (l * 3 + 2) * NPIX;
    const int base = blockIdx.x * PB;

    // ---- Phase 1: prep 8 px/thread (2 passes), store fp16 ----
    #pragma unroll
    for (int pass = 0; pass < 2; pass++) {
        const int ploc = pass * 1024 + tid * 4;
        const float4 r0 = *(const float4*)&x0p[base + ploc];
        const float4 r1 = *(const float4*)&x1p[base + ploc];
        const float4 r2 = *(const float4*)&x2p[base + ploc];
        float4 U4, V4, W4;
        #define PREP(E) { \
            const float v0 = fminf(fmaxf(r0.E, 0.0f), 1.0f); \
            const float v1 = fminf(fmaxf(r1.E, 0.0f), 1.0f); \
            const float v2 = fminf(fmaxf(r2.E, 0.0f), 1.0f); \
            W4.E = __builtin_amdgcn_sqrtf(fmaf(v0, v0, fmaf(v1, v1, fmaf(v2, v2, EPSF)))); \
            const float lg0 = __builtin_amdgcn_logf(v0 + EPSF); \
            const float lg1 = __builtin_amdgcn_logf(v1 + EPSF); \
            const float lg2 = __builtin_amdgcn_logf(v2 + EPSF); \
            float U, V; \
            if (c == 0)      { U = lg0 - lg1; V = lg0 - lg2; } \
            else if (c == 1) { U = lg1 - lg0; V = lg1 - lg2; } \
            else             { U = lg2 - lg0; V = lg2 - lg1; } \
            U4.E = LN2_50 * U; V4.E = LN2_50 * V; }
        PREP(x) PREP(y) PREP(z) PREP(w)
        #undef PREP
        *(h4*)&sUh[ploc] = h4{(_Float16)U4.x, (_Float16)U4.y, (_Float16)U4.z, (_Float16)U4.w};
        *(h4*)&sVh[ploc] = h4{(_Float16)V4.x, (_Float16)V4.y, (_Float16)V4.z, (_Float16)V4.w};
        *(h4*)&sWh[ploc] = h4{(_Float16)W4.x, (_Float16)W4.y, (_Float16)W4.z, (_Float16)W4.w};
    }
    __syncthreads();

    // ---- Phase 2: packed-fp16 eval + MFMA over this wave's 512-px slice ----
    const float step50 = 50.0f * (6.0f / 63.0f);
    const float ou0 = -150.0f + step50 * (float)ln;
    const float ou1 = ou0 + step50 * 32.0f;
    const h2 o0_2 = {(_Float16)ou0, (_Float16)ou0};
    const h2 o1_2 = {(_Float16)ou1, (_Float16)ou1};
    const h2 one2   = {(_Float16)1.0f, (_Float16)1.0f};
    const h2 two2   = {(_Float16)2.0f, (_Float16)2.0f};
    const h2 clamp2 = {(_Float16)16384.0f, (_Float16)16384.0f};
    const s2 magic2 = {(short)0x779A, (short)0x779A};

    f32x16 acc00, acc01, acc10, acc11;
    #pragma unroll
    for (int i = 0; i < 16; i++) { acc00[i] = 0.f; acc01[i] = 0.f; acc10[i] = 0.f; acc11[i] = 0.f; }

    const int wbase = wv * 512;
    #pragma unroll 2
    for (int ks = 0; ks < 32; ks++) {
        const int kb = wbase + ks * 16 + hf * 8;     // half-wave's 8 k-pixels
        H8p U, V, W, A0, A1, B0, B1;
        U.v8 = *(const h8*)&sUh[kb];
        V.v8 = *(const h8*)&sVh[kb];
        W.v8 = *(const h8*)&sWh[kb];
        #pragma unroll
        for (int q = 0; q < 4; q++) {
            A0.h[q] = W.h[q] * kev2(U.h[q], o0_2, one2, two2, clamp2, magic2);
            A1.h[q] = W.h[q] * kev2(U.h[q], o1_2, one2, two2, clamp2, magic2);
            B0.h[q] = kev2(V.h[q], o0_2, one2, two2, clamp2, magic2);
            B1.h[q] = kev2(V.h[q], o1_2, one2, two2, clamp2, magic2);
        }
        acc00 = __builtin_amdgcn_mfma_f32_32x32x16_f16(A0.v8, B0.v8, acc00, 0, 0, 0);
        acc01 = __builtin_amdgcn_mfma_f32_32x32x16_f16(A0.v8, B1.v8, acc01, 0, 0, 0);
        acc10 = __builtin_amdgcn_mfma_f32_32x32x16_f16(A1.v8, B0.v8, acc10, 0, 0, 0);
        acc11 = __builtin_amdgcn_mfma_f32_32x32x16_f16(A1.v8, B1.v8, acc11, 0, 0, 0);
    }

    // merge 4 wave accumulators (C/D layout: col=ln, row=(r&3)+8*(r>>2)+4*hf)
    #pragma unroll
    for (int r = 0; r < 16; r++) {
        const int row = (r & 3) + 8 * (r >> 2) + 4 * hf;
        atomicAdd(&sHist[row * 64 + ln],             acc00[r]);
        atomicAdd(&sHist[row * 64 + 32 + ln],        acc01[r]);
        atomicAdd(&sHist[(row + 32) * 64 + ln],      acc10[r]);
        atomicAdd(&sHist[(row + 32) * 64 + 32 + ln], acc11[r]);
    }
    __syncthreads();

    if (atomic_mode == 0) {
        // plain coalesced partial store: partial[chunk][lc][4096]
        float* __restrict__ g = dst + (blockIdx.x * LC + lc) * (H * H);
        #pragma unroll
        for (int r = 0; r < 4; r++) {
            const int i = (r * 256 + tid) * 4;
            *(float4*)&g[i] = *(const float4*)&sHist[i];
        }
    } else {
        float* __restrict__ g = dst + lc * (H * H);
        #pragma unroll
        for (int r = 0; r < 16; r++) {
            const int i = r * 256 + tid;
            unsafeAtomicAdd(&g[i], sHist[i]);
        }
    }
}

// out[lc][i] = sum over 32 chunk-partials (plain loads, fully parallel)
__global__ __launch_bounds__(256) void hist_reduce(const float* __restrict__ part,
                                                   float* __restrict__ out) {
    const int lc  = blockIdx.x >> 4;
    const int seg = blockIdx.x & 15;
    const int i   = lc * (H * H) + seg * 256 + threadIdx.x;
    float s = 0.0f;
    #pragma unroll
    for (int sc = 0; sc < S_CHUNKS; sc++)
        s += part[sc * (LC * H * H) + i];
    out[i] = s;
}

// fused total + normalize: one block per sample l
__global__ __launch_bounds__(256) void hist_finish(float* __restrict__ out) {
    const int l = blockIdx.x;
    float* __restrict__ p = out + l * 3 * H * H;
    float s = 0.0f;
    #pragma unroll
    for (int it = 0; it < 12; it++) {
        const float4 v = *(const float4*)&p[(it * 256 + threadIdx.x) * 4];
        s += (v.x + v.y) + (v.z + v.w);
    }
    #pragma unroll
    for (int off = 32; off > 0; off >>= 1) s += __shfl_down(s, off, 64);
    __shared__ float ps[4];
    if ((threadIdx.x & 63) == 0) ps[threadIdx.x >> 6] = s;
    __syncthreads();
    const float T = (ps[0] + ps[1]) + (ps[2] + ps[3]);
    const float inv = 1.0f / (T + EPSF);
    #pragma unroll
    for (int it = 0; it < 12; it++) {
        float4 v = *(const float4*)&p[(it * 256 + threadIdx.x) * 4];
        v.x *= inv; v.y *= inv; v.z *= inv; v.w *= inv;
        *(float4*)&p[(it * 256 + threadIdx.x) * 4] = v;
    }
}

extern "C" void kernel_launch(void* const* d_in, const int* in_sizes, int n_in,
                              void* d_out, int out_size, void* d_ws, size_t ws_size,
                              hipStream_t stream) {
    const float* x = (const float*)d_in[0];
    float* out = (float*)d_out;
    float* ws  = (float*)d_ws;

    if (ws_size >= NEED_WS) {
        // partials path: no global atomics anywhere
        hipLaunchKernelGGL(hist_main,   dim3(S_CHUNKS, LC), dim3(256), 0, stream, x, ws, 0);
        hipLaunchKernelGGL(hist_reduce, dim3(LC * 16),      dim3(256), 0, stream, ws, out);
        hipLaunchKernelGGL(hist_finish, dim3(LBATCH),       dim3(256), 0, stream, out);
    } else {
        // fallback: atomic accumulation into out
        hipLaunchKernelGGL(hist_zero,   dim3(LC * H * H / 256), dim3(256), 0, stream, out);
        hipLaunchKernelGGL(hist_main,   dim3(S_CHUNKS, LC),     dim3(256), 0, stream, x, out, 1);
        hipLaunchKernelGGL(hist_finish, dim3(LBATCH),           dim3(256), 0, stream, out);
    }
}

// Round 7
// 152.643 us; speedup vs baseline: 1.3578x; 1.0100x over previous
//
#include <hip/hip_runtime.h>

#define H 64
#define NPIX 65536
#define LBATCH 8
#define LC 24
#define S_CHUNKS 32
#define PB 2048            // pixels per block
#define EPSF 1e-6f
#define LN2_50 34.6573590f // 50 * ln(2): U50 = 50*(ln a - ln b) = LN2_50*(log2 a - log2 b)

// ws: partials [S_CHUNKS][LC][H*H] + per-(lc,seg) sums [LC*16]
#define WS_PART ((size_t)S_CHUNKS * LC * H * H)
#define NEED_WS ((WS_PART + LC * 16) * 4)

typedef _Float16 h8 __attribute__((ext_vector_type(8)));   // MFMA operand
typedef _Float16 h4 __attribute__((ext_vector_type(4)));
typedef _Float16 h2 __attribute__((ext_vector_type(2)));
typedef short    s2 __attribute__((ext_vector_type(2)));
typedef float f32x16 __attribute__((ext_vector_type(16)));
union H8p { h8 v8; h2 h[4]; };

#if __has_builtin(__builtin_elementwise_fma)
#define FMA2(a, b, c) __builtin_elementwise_fma((a), (b), (c))
#else
#define FMA2(a, b, c) ((a) * (b) + (c))
#endif

// Full-rate packed-fp16 eval of 1/(1+d^2): int-magic seed + 2 packed Newton
// steps. Zero trans-pipe ops. x clamped to 16384 (tail values <=6e-5).
static __device__ __forceinline__ h2 kev2(h2 u2, h2 o2, h2 one2, h2 two2,
                                          h2 clamp2, s2 magic2) {
    const h2 d  = u2 - o2;
    const h2 xx = __builtin_elementwise_min(FMA2(d, d, one2), clamp2);
    h2 y = __builtin_bit_cast(h2, (s2)(magic2 - __builtin_bit_cast(s2, xx)));
    y = y * FMA2(-xx, y, two2);
    y = y * FMA2(-xx, y, two2);
    return y;
}

__global__ __launch_bounds__(256) void hist_zero(float* __restrict__ out) {
    out[blockIdx.x * 256 + threadIdx.x] = 0.0f;
}

// One block per (lc, 2048-px chunk). Phase 1: stage fp16 U50/V50/w (12 KB).
// Phase 2: 32 K-steps/wave of (3 broadcast ds_read_b128 -> pk-fp16 evals ->
// 4 mfma_f32_32x32x16_f16). launch_bounds(256,2): 256 unified regs/wave so the
// 16 independent kev2 chains per K-step can actually be in flight (at (256,4)
// the allocator squeezed to 48 VGPRs and serialized them -- R6's 78% stall).
__global__ __launch_bounds__(256, 2) void hist_main(const float* __restrict__ x,
                                                    float* __restrict__ dst,
                                                    int atomic_mode) {
    __shared__ _Float16 sUh[PB];
    __shared__ _Float16 sVh[PB];
    __shared__ _Float16 sWh[PB];
    __shared__ float sHist[H * H];

    const int tid  = threadIdx.x;
    const int wv   = tid >> 6;
    const int lane = tid & 63;
    const int hf   = lane >> 5;
    const int ln   = lane & 31;
    const int lc   = blockIdx.y;
    const int l    = lc / 3;
    const int c    = lc - 3 * l;

    #pragma unroll
    for (int r = 0; r < 4; r++)
        *(float4*)&sHist[(r * 256 + tid) * 4] = make_float4(0.f, 0.f, 0.f, 0.f);

    const float* __restrict__ x0p = x + (l * 3 + 0) * NPIX;
    const float* __restrict__ x1p = x + (l * 3 + 1) * NPIX;
    const float* __restrict__ x2p = x + (l * 3 + 2) * NPIX;
    const int base = blockIdx.x * PB;

    // ---- Phase 1: prep 8 px/thread (2 passes), store fp16 ----
    #pragma unroll
    for (int pass = 0; pass < 2; pass++) {
        const int ploc = pass * 1024 + tid * 4;
        const float4 r0 = *(const float4*)&x0p[base + ploc];
        const float4 r1 = *(const float4*)&x1p[base + ploc];
        const float4 r2 = *(const float4*)&x2p[base + ploc];
        float4 U4, V4, W4;
        #define PREP(E) { \
            const float v0 = fminf(fmaxf(r0.E, 0.0f), 1.0f); \
            const float v1 = fminf(fmaxf(r1.E, 0.0f), 1.0f); \
            const float v2 = fminf(fmaxf(r2.E, 0.0f), 1.0f); \
            W4.E = __builtin_amdgcn_sqrtf(fmaf(v0, v0, fmaf(v1, v1, fmaf(v2, v2, EPSF)))); \
            const float lg0 = __builtin_amdgcn_logf(v0 + EPSF); \
            const float lg1 = __builtin_amdgcn_logf(v1 + EPSF); \
            const float lg2 = __builtin_amdgcn_logf(v2 + EPSF); \
            float U, V; \
            if (c == 0)      { U = lg0 - lg1; V = lg0 - lg2; } \
            else if (c == 1) { U = lg1 - lg0; V = lg1 - lg2; } \
            else             { U = lg2 - lg0; V = lg2 - lg1; } \
            U4.E = LN2_50 * U; V4.E = LN2_50 * V; }
        PREP(x) PREP(y) PREP(z) PREP(w)
        #undef PREP
        *(h4*)&sUh[ploc] = h4{(_Float16)U4.x, (_Float16)U4.y, (_Float16)U4.z, (_Float16)U4.w};
        *(h4*)&sVh[ploc] = h4{(_Float16)V4.x, (_Float16)V4.y, (_Float16)V4.z, (_Float16)V4.w};
        *(h4*)&sWh[ploc] = h4{(_Float16)W4.x, (_Float16)W4.y, (_Float16)W4.z, (_Float16)W4.w};
    }
    __syncthreads();

    // ---- Phase 2: packed-fp16 eval + MFMA over this wave's 512-px slice ----
    const float step50 = 50.0f * (6.0f / 63.0f);
    const float ou0 = -150.0f + step50 * (float)ln;
    const float ou1 = ou0 + step50 * 32.0f;
    const h2 o0_2 = {(_Float16)ou0, (_Float16)ou0};
    const h2 o1_2 = {(_Float16)ou1, (_Float16)ou1};
    const h2 one2   = {(_Float16)1.0f, (_Float16)1.0f};
    const h2 two2   = {(_Float16)2.0f, (_Float16)2.0f};
    const h2 clamp2 = {(_Float16)16384.0f, (_Float16)16384.0f};
    const s2 magic2 = {(short)0x779A, (short)0x779A};

    f32x16 acc00, acc01, acc10, acc11;
    #pragma unroll
    for (int i = 0; i < 16; i++) { acc00[i] = 0.f; acc01[i] = 0.f; acc10[i] = 0.f; acc11[i] = 0.f; }

    const int wbase = wv * 512;
    #pragma unroll 4
    for (int ks = 0; ks < 32; ks++) {
        const int kb = wbase + ks * 16 + hf * 8;     // half-wave's 8 k-pixels
        H8p U, V, W, A0, A1, B0, B1;
        U.v8 = *(const h8*)&sUh[kb];
        V.v8 = *(const h8*)&sVh[kb];
        W.v8 = *(const h8*)&sWh[kb];
        #pragma unroll
        for (int q = 0; q < 4; q++) {
            A0.h[q] = W.h[q] * kev2(U.h[q], o0_2, one2, two2, clamp2, magic2);
            A1.h[q] = W.h[q] * kev2(U.h[q], o1_2, one2, two2, clamp2, magic2);
            B0.h[q] = kev2(V.h[q], o0_2, one2, two2, clamp2, magic2);
            B1.h[q] = kev2(V.h[q], o1_2, one2, two2, clamp2, magic2);
        }
        acc00 = __builtin_amdgcn_mfma_f32_32x32x16_f16(A0.v8, B0.v8, acc00, 0, 0, 0);
        acc01 = __builtin_amdgcn_mfma_f32_32x32x16_f16(A0.v8, B1.v8, acc01, 0, 0, 0);
        acc10 = __builtin_amdgcn_mfma_f32_32x32x16_f16(A1.v8, B0.v8, acc10, 0, 0, 0);
        acc11 = __builtin_amdgcn_mfma_f32_32x32x16_f16(A1.v8, B1.v8, acc11, 0, 0, 0);
    }

    // merge 4 wave accumulators (C/D layout: col=ln, row=(r&3)+8*(r>>2)+4*hf)
    #pragma unroll
    for (int r = 0; r < 16; r++) {
        const int row = (r & 3) + 8 * (r >> 2) + 4 * hf;
        atomicAdd(&sHist[row * 64 + ln],             acc00[r]);
        atomicAdd(&sHist[row * 64 + 32 + ln],        acc01[r]);
        atomicAdd(&sHist[(row + 32) * 64 + ln],      acc10[r]);
        atomicAdd(&sHist[(row + 32) * 64 + 32 + ln], acc11[r]);
    }
    __syncthreads();

    if (atomic_mode == 0) {
        // plain coalesced partial store: partial[chunk][lc][4096]
        float* __restrict__ g = dst + (blockIdx.x * LC + lc) * (H * H);
        #pragma unroll
        for (int r = 0; r < 4; r++) {
            const int i = (r * 256 + tid) * 4;
            *(float4*)&g[i] = *(const float4*)&sHist[i];
        }
    } else {
        float* __restrict__ g = dst + lc * (H * H);
        #pragma unroll
        for (int r = 0; r < 16; r++) {
            const int i = r * 256 + tid;
            unsafeAtomicAdd(&g[i], sHist[i]);
        }
    }
}

// out[lc][i] = sum of 32 chunk-partials; also emit per-(lc,seg) sum for norm
__global__ __launch_bounds__(256) void hist_reduce(const float* __restrict__ part,
                                                   float* __restrict__ out,
                                                   float* __restrict__ sums) {
    const int lc  = blockIdx.x >> 4;
    const int seg = blockIdx.x & 15;
    const int i   = lc * (H * H) + seg * 256 + threadIdx.x;
    float s = 0.0f;
    #pragma unroll
    for (int sc = 0; sc < S_CHUNKS; sc++)
        s += part[sc * (LC * H * H) + i];
    out[i] = s;
    // block-level sum -> sums[lc*16+seg]
    float t = s;
    #pragma unroll
    for (int off = 32; off > 0; off >>= 1) t += __shfl_down(t, off, 64);
    __shared__ float ps[4];
    if ((threadIdx.x & 63) == 0) ps[threadIdx.x >> 6] = t;
    __syncthreads();
    if (threadIdx.x == 0) sums[blockIdx.x] = (ps[0] + ps[1]) + (ps[2] + ps[3]);
}

// wide normalize: 384 blocks; sample l's total = sum of its 48 (lc,seg) sums
__global__ __launch_bounds__(256) void hist_norm(float* __restrict__ out,
                                                 const float* __restrict__ sums) {
    const int i = blockIdx.x * 256 + threadIdx.x;
    const int l = blockIdx.x / 48;          // 48 blocks per sample
    float T = 0.0f;
    #pragma unroll
    for (int k = 0; k < 48; k++) T += sums[l * 48 + k];
    out[i] = out[i] / (T + EPSF);
}

// fallback finish (atomic path): one block per sample
__global__ __launch_bounds__(256) void hist_finish(float* __restrict__ out) {
    const int l = blockIdx.x;
    float* __restrict__ p = out + l * 3 * H * H;
    float s = 0.0f;
    #pragma unroll
    for (int it = 0; it < 12; it++) {
        const float4 v = *(const float4*)&p[(it * 256 + threadIdx.x) * 4];
        s += (v.x + v.y) + (v.z + v.w);
    }
    #pragma unroll
    for (int off = 32; off > 0; off >>= 1) s += __shfl_down(s, off, 64);
    __shared__ float ps[4];
    if ((threadIdx.x & 63) == 0) ps[threadIdx.x >> 6] = s;
    __syncthreads();
    const float T = (ps[0] + ps[1]) + (ps[2] + ps[3]);
    const float inv = 1.0f / (T + EPSF);
    #pragma unroll
    for (int it = 0; it < 12; it++) {
        float4 v = *(const float4*)&p[(it * 256 + threadIdx.x) * 4];
        v.x *= inv; v.y *= inv; v.z *= inv; v.w *= inv;
        *(float4*)&p[(it * 256 + threadIdx.x) * 4] = v;
    }
}

extern "C" void kernel_launch(void* const* d_in, const int* in_sizes, int n_in,
                              void* d_out, int out_size, void* d_ws, size_t ws_size,
                              hipStream_t stream) {
    const float* x = (const float*)d_in[0];
    float* out = (float*)d_out;
    float* ws  = (float*)d_ws;

    if (ws_size >= NEED_WS) {
        float* sums = ws + WS_PART;
        hipLaunchKernelGGL(hist_main,   dim3(S_CHUNKS, LC),      dim3(256), 0, stream, x, ws, 0);
        hipLaunchKernelGGL(hist_reduce, dim3(LC * 16),           dim3(256), 0, stream, ws, out, sums);
        hipLaunchKernelGGL(hist_norm,   dim3(LC * H * H / 256),  dim3(256), 0, stream, out, sums);
    } else {
        hipLaunchKernelGGL(hist_zero,   dim3(LC * H * H / 256), dim3(256), 0, stream, out);
        hipLaunchKernelGGL(hist_main,   dim3(S_CHUNKS, LC),     dim3(256), 0, stream, x, out, 1);
        hipLaunchKernelGGL(hist_finish, dim3(LBATCH),           dim3(256), 0, stream, out);
    }
}